// Round 8
// baseline (554.028 us; speedup 1.0000x reference)
//
#include <hip/hip_runtime.h>

typedef unsigned short u16;
typedef unsigned int u32;

#define T_SEQ 2048
#define NHEAD 16
#define HDIM 64
#define CDIM 1024
#define W_HSTR (512*2048)
#define Z_HSTR (2048*512)

// Octonion sign table: SG[a][n] = sign of component (a^n) of e_a * e_n.
// Byte a holds row a; bit n set => negative. (Validated end-to-end rounds 3-7.)
#define SGBITS 0xB2D8741EACC66A00ULL

// exp(s*0.125) = exp2(s*0.125/ln2); extra 2^-12 scale keeps unnormalized Z in fp16 range.
#define EXP2C 0.18033688011112042f

typedef _Float16 f16x8 __attribute__((ext_vector_type(8)));
typedef float f32x4 __attribute__((ext_vector_type(4)));

__device__ __forceinline__ float h2f(u16 u) { _Float16 h; __builtin_memcpy(&h, &u, 2); return (float)h; }
__device__ __forceinline__ u16 f2h(float f) { _Float16 h = (_Float16)f; u16 u; __builtin_memcpy(&u, &h, 2); return u; }
__device__ __forceinline__ u32 pk(float a, float b) { return (u32)f2h(a) | ((u32)f2h(b) << 16); }

// async 16B/lane global->LDS DMA; lds dest wave-uniform (HW adds lane*16)
__device__ __forceinline__ void gload16(const u16* g, u16* l) {
    __builtin_amdgcn_global_load_lds((const __attribute__((address_space(1))) u32*)g,
                                     (__attribute__((address_space(3))) u32*)l, 16, 0, 0);
}

// ---- MFMA tile core (conflict-free fragment-major LDS; rounds 6-7) ----
template<bool F16OUT>
__device__ __forceinline__ void hgemm_tile(const u16* __restrict__ At, int lda,
                                           const u16* __restrict__ Bt, int ldb, int K,
                                           float* __restrict__ Cf, u16* __restrict__ Ch,
                                           int ldc, float scale, u16* As, u16* Bs) {
    int t = threadIdx.x;
    int wave = t >> 6, l = t & 63;
    int wm = wave & 1, wn = wave >> 1;
    int quad = l >> 4, lr = l & 15;
    f32x4 acc[4][4];
#pragma unroll
    for (int i = 0; i < 4; ++i)
#pragma unroll
        for (int j = 0; j < 4; ++j) acc[i][j] = (f32x4){0.f, 0.f, 0.f, 0.f};
    int acol = quad * 8;
    for (int k0 = 0; k0 < K; k0 += 64) {
#pragma unroll
        for (int j = 0; j < 4; ++j) {
            int d = wave * 4 + j;
            int kb = d >> 3, seg = d & 7;
            size_t roff = (size_t)(seg * 16 + lr);
            int coff = k0 + kb * 32 + acol;
            gload16(At + roff * lda + coff, As + d * 512);
            gload16(Bt + roff * ldb + coff, Bs + d * 512);
        }
        __syncthreads();
#pragma unroll
        for (int kb = 0; kb < 2; ++kb) {
            f16x8 af[4], bf[4];
#pragma unroll
            for (int mi = 0; mi < 4; ++mi) af[mi] = *(const f16x8*)&As[(kb * 8 + wm * 4 + mi) * 512 + l * 8];
#pragma unroll
            for (int ni = 0; ni < 4; ++ni) bf[ni] = *(const f16x8*)&Bs[(kb * 8 + wn * 4 + ni) * 512 + l * 8];
#pragma unroll
            for (int mi = 0; mi < 4; ++mi)
#pragma unroll
                for (int ni = 0; ni < 4; ++ni)
                    acc[mi][ni] = __builtin_amdgcn_mfma_f32_16x16x32_f16(af[mi], bf[ni], acc[mi][ni], 0, 0, 0);
        }
        __syncthreads();
    }
#pragma unroll
    for (int mi = 0; mi < 4; ++mi)
#pragma unroll
        for (int ni = 0; ni < 4; ++ni)
#pragma unroll
            for (int rr = 0; rr < 4; ++rr) {
                int gr = wm * 64 + mi * 16 + quad * 4 + rr;
                int gc = wn * 64 + ni * 16 + lr;
                float v = acc[mi][ni][rr] * scale;
                if (F16OUT) Ch[(size_t)gr * ldc + gc] = f2h(v);
                else Cf[(size_t)gr * ldc + gc] = v;
            }
}

__global__ __launch_bounds__(256) void hgemm_f32(const u16* __restrict__ A, int lda,
                                                 const u16* __restrict__ B, int ldb,
                                                 float* __restrict__ C, int ldc, int K) {
    __shared__ u16 As[8192], Bs[8192];
    int bm = blockIdx.y * 128, bn = blockIdx.x * 128;
    hgemm_tile<false>(A + (size_t)bm * lda, lda, B + (size_t)bn * ldb, ldb, K,
                      C + (size_t)bm * ldc + bn, nullptr, ldc, 1.f, As, Bs);
}

// ---- fused causal attention core: S=QK^T -> p'=exp2(c*s-12) -> Z'=P.W ; l only on nq==0 ----
// Normalization (1/l) deferred to contract_y: Sum_a q_a Z'_a / l == (Sum_a q_a Z'_a)/l.
__global__ __launch_bounds__(256, 4) void flash_pw(const u16* __restrict__ q16,
                                                   const u16* __restrict__ k16,
                                                   const u16* __restrict__ W,
                                                   u16* __restrict__ Z,
                                                   float* __restrict__ lbuf) {
    __shared__ u16 Pl[128 * 136];
    int idx = blockIdx.x;
    int rb = 15 - (idx >> 6);
    int i6 = idx & 63;
    int h = ((i6 & 7) << 1) | ((i6 >> 3) & 1);  // same-h blocks share an XCD (L2 W-locality)
    int nq = i6 >> 4;
    int t = threadIdx.x;
    int wave = t >> 6, l = t & 63;
    int wm = wave & 1, wn = wave >> 1;
    int quad = l >> 4, lr = l & 15;

    const u16* qbase = q16 + (size_t)(rb * 128 + wm * 64 + lr) * CDIM + h * HDIM + quad * 8;
    f16x8 qa[4][2];
#pragma unroll
    for (int mi = 0; mi < 4; ++mi)
#pragma unroll
        for (int kb = 0; kb < 2; ++kb)
            qa[mi][kb] = *(const f16x8*)(qbase + (size_t)(mi * 16) * CDIM + kb * 32);

    f32x4 accz[4][4];
    f32x4 accl[4];
#pragma unroll
    for (int mi = 0; mi < 4; ++mi) {
        accl[mi] = (f32x4){0.f, 0.f, 0.f, 0.f};
#pragma unroll
        for (int ni = 0; ni < 4; ++ni) accz[mi][ni] = (f32x4){0.f, 0.f, 0.f, 0.f};
    }
    f16x8 ones;
#pragma unroll
    for (int j = 0; j < 8; ++j) ones[j] = (_Float16)1.0f;

    const u16* kbase = k16 + (size_t)(wn * 64 + lr) * CDIM + h * HDIM + quad * 8;
    const u16* Wbase = W + (size_t)h * W_HSTR + (size_t)(nq * 128 + wn * 64 + lr) * T_SEQ + quad * 8;

    for (int cb = 0; cb <= rb; ++cb) {
        f16x8 kf[4][2];
#pragma unroll
        for (int ni = 0; ni < 4; ++ni)
#pragma unroll
            for (int kb = 0; kb < 2; ++kb)
                kf[ni][kb] = *(const f16x8*)(kbase + (size_t)(cb * 128 + ni * 16) * CDIM + kb * 32);
        f32x4 s[4][4];
#pragma unroll
        for (int mi = 0; mi < 4; ++mi)
#pragma unroll
            for (int ni = 0; ni < 4; ++ni) s[mi][ni] = (f32x4){0.f, 0.f, 0.f, 0.f};
#pragma unroll
        for (int kb = 0; kb < 2; ++kb)
#pragma unroll
            for (int mi = 0; mi < 4; ++mi)
#pragma unroll
                for (int ni = 0; ni < 4; ++ni)
                    s[mi][ni] = __builtin_amdgcn_mfma_f32_16x16x32_f16(qa[mi][kb], kf[ni][kb], s[mi][ni], 0, 0, 0);
        // p' = exp2(s*c - 12), causal mask on diagonal tile; write P' to LDS (C-layout scatter)
#pragma unroll
        for (int mi = 0; mi < 4; ++mi) {
            int row = wm * 64 + mi * 16 + quad * 4;
#pragma unroll
            for (int ni = 0; ni < 4; ++ni) {
                int col = wn * 64 + ni * 16 + lr;
#pragma unroll
                for (int rr = 0; rr < 4; ++rr) {
                    bool valid = (cb < rb) | (col <= row + rr);
                    float p = valid ? __builtin_amdgcn_exp2f(s[mi][ni][rr] * EXP2C - 12.f) : 0.f;
                    Pl[(row + rr) * 136 + col] = f2h(p);
                }
            }
        }
        __syncthreads();
#pragma unroll
        for (int kb = 0; kb < 4; ++kb) {
            f16x8 pf[4], wf[4];
#pragma unroll
            for (int ni = 0; ni < 4; ++ni)
                wf[ni] = *(const f16x8*)(Wbase + (size_t)(ni * 16) * T_SEQ + cb * 128 + kb * 32);
#pragma unroll
            for (int mi = 0; mi < 4; ++mi)
                pf[mi] = *(const f16x8*)&Pl[(wm * 64 + mi * 16 + lr) * 136 + kb * 32 + quad * 8];
#pragma unroll
            for (int mi = 0; mi < 4; ++mi) {
#pragma unroll
                for (int ni = 0; ni < 4; ++ni)
                    accz[mi][ni] = __builtin_amdgcn_mfma_f32_16x16x32_f16(pf[mi], wf[ni], accz[mi][ni], 0, 0, 0);
                if (nq == 0)
                    accl[mi] = __builtin_amdgcn_mfma_f32_16x16x32_f16(pf[mi], ones, accl[mi], 0, 0, 0);
            }
        }
        __syncthreads();
    }
    u16* Zb = Z + (size_t)h * Z_HSTR;
#pragma unroll
    for (int mi = 0; mi < 4; ++mi)
#pragma unroll
        for (int rr = 0; rr < 4; ++rr) {
            int row = rb * 128 + wm * 64 + mi * 16 + quad * 4 + rr;
#pragma unroll
            for (int ni = 0; ni < 4; ++ni) {
                int col = nq * 128 + wn * 64 + ni * 16 + lr;
                Zb[(size_t)row * 512 + col] = f2h(accz[mi][ni][rr]);
            }
        }
    if (nq == 0 && lr == 0) {
#pragma unroll
        for (int mi = 0; mi < 4; ++mi) {
            int row = rb * 128 + wm * 64 + mi * 16 + quad * 4;
            *(f32x4*)(lbuf + h * T_SEQ + row) = accl[mi];
        }
    }
}

// fp32 -> fp16 conversions: z=0 x(2M), z=1..4 Wq/Wk/Wv/Wo (1M each) into w16
__global__ __launch_bounds__(256) void cvt5(const float* __restrict__ x, const float* __restrict__ wq,
                                            const float* __restrict__ wk, const float* __restrict__ wv,
                                            const float* __restrict__ wo,
                                            u16* __restrict__ x16, u16* __restrict__ w16) {
    int z = blockIdx.y;
    size_t base = ((size_t)blockIdx.x * 256 + threadIdx.x) * 8;
    const float* src;
    u16* dst;
    size_t cnt;
    if (z == 0) { src = x; dst = x16; cnt = 2097152; }
    else if (z == 1) { src = wq; dst = w16; cnt = 1048576; }
    else if (z == 2) { src = wk; dst = w16 + 1048576; cnt = 1048576; }
    else if (z == 3) { src = wv; dst = w16 + 2097152; cnt = 1048576; }
    else { src = wo; dst = w16 + 3145728; cnt = 1048576; }
    if (base >= cnt) return;
    float4 f0 = *(const float4*)(src + base);
    float4 f1 = *(const float4*)(src + base + 4);
    uint4 o;
    o.x = pk(f0.x, f0.y); o.y = pk(f0.z, f0.w); o.z = pk(f1.x, f1.y); o.w = pk(f1.z, f1.w);
    *(uint4*)(dst + base) = o;
}

// One wave per (t,h): rotary+RMS for q,k from fused qkv (ld 3072); writes q16,k16 (fp16), kc (fp32).
__global__ __launch_bounds__(256) void prep_rope(const float* __restrict__ qkv,
                                                 u16* __restrict__ q16, u16* __restrict__ k16,
                                                 float* __restrict__ kc,
                                                 const float* __restrict__ cosb, const float* __restrict__ sinb) {
    int wave = threadIdx.x >> 6, lane = threadIdx.x & 63;
    int idx = blockIdx.x * 4 + wave;
    int t = idx >> 4, h = idx & 15;
    int d = lane & 31;
    float cs = cosb[t * 32 + d];
    float sn = sinb[t * 32 + d];
    size_t b3 = (size_t)t * 3072 + h * HDIM;
    size_t b1 = (size_t)t * CDIM + h * HDIM;

    float xq = qkv[b3 + lane];
    float oq = __shfl(xq, lane ^ 32);
    float rq = (lane < 32) ? fmaf(xq, cs, oq * sn) : fmaf(xq, cs, -oq * sn);
    float ssq = rq * rq;
#pragma unroll
    for (int m = 1; m < 64; m <<= 1) ssq += __shfl_xor(ssq, m);
    rq *= rsqrtf(ssq * (1.f / 64.f) + 1e-6f);
    q16[b1 + lane] = f2h(rq);

    float xk = qkv[b3 + 1024 + lane];
    float ok = __shfl(xk, lane ^ 32);
    float rk = (lane < 32) ? fmaf(xk, cs, ok * sn) : fmaf(xk, cs, -ok * sn);
    float ssk = rk * rk;
#pragma unroll
    for (int m = 1; m < 64; m <<= 1) ssk += __shfl_xor(ssk, m);
    rk *= rsqrtf(ssk * (1.f / 64.f) + 1e-6f);
    k16[b1 + lane] = f2h(rk);

    float s8 = rk * rk;
    s8 += __shfl_xor(s8, 1); s8 += __shfl_xor(s8, 2); s8 += __shfl_xor(s8, 4);
    float sc2 = 1.f / fmaxf(sqrtf(s8), 1e-12f);
    float kcv = rk * sc2;
    if (lane & 7) kcv = -kcv;  // octonion conjugate
    kc[b1 + lane] = kcv;
}

// W[h][n=(m*64+a*8+e)][j] from kc (fp32, ld 1024) and v inside qkv (fp32, ld 3072, +2048)
__global__ __launch_bounds__(256) void w_pre(const float* __restrict__ kc, const float* __restrict__ qkv,
                                             u16* __restrict__ W) {
    __shared__ float kcs[64][65];
    __shared__ float vs[64][65];
    int h = blockIdx.y;
    int j0 = blockIdx.x * 64;
    int t = threadIdx.x;
    int r = t >> 2, cq = (t & 3) * 16;
    const float* kp = kc + (size_t)(j0 + r) * CDIM + h * HDIM + cq;
    const float* vp = qkv + (size_t)(j0 + r) * 3072 + 2048 + h * HDIM + cq;
#pragma unroll
    for (int u4 = 0; u4 < 4; ++u4) {
        float4 a = *(const float4*)(kp + u4 * 4);
        float4 b = *(const float4*)(vp + u4 * 4);
        kcs[r][cq + u4 * 4 + 0] = a.x; kcs[r][cq + u4 * 4 + 1] = a.y;
        kcs[r][cq + u4 * 4 + 2] = a.z; kcs[r][cq + u4 * 4 + 3] = a.w;
        vs[r][cq + u4 * 4 + 0] = b.x; vs[r][cq + u4 * 4 + 1] = b.y;
        vs[r][cq + u4 * 4 + 2] = b.z; vs[r][cq + u4 * 4 + 3] = b.w;
    }
    __syncthreads();
    int j = t & 63, g = t >> 6;
    u16* Wp = W + (size_t)h * W_HSTR + j0 + j;
    for (int ae = g * 16; ae < g * 16 + 16; ++ae) {
        int a = ae >> 3, e = ae & 7;
        u32 mask = 0;
#pragma unroll
        for (int qq = 0; qq < 8; ++qq) {
            int p = a ^ e ^ qq;
            u32 bit = (u32)(((SGBITS >> (a * 8 + p)) ^ (SGBITS >> ((e ^ qq) * 8 + qq))) & 1ULL);
            mask |= bit << qq;
        }
#pragma unroll
        for (int m = 0; m < 8; ++m) {
            float w = 0.f;
#pragma unroll
            for (int qq = 0; qq < 8; ++qq) {
                float t1 = kcs[j][m * 8 + (a ^ e ^ qq)] * vs[j][m * 8 + qq];
                w = ((mask >> qq) & 1) ? (w - t1) : (w + t1);
            }
            Wp[(size_t)(m * 64 + ae) * T_SEQ] = f2h(w);
        }
    }
}

// y16[i, h*64+m*8+e] = (sum_a q16[..m*8+a] * Z'[h][i][m*64+a*8+e]) / l[h][i]
__global__ __launch_bounds__(256) void contract_y(const u16* __restrict__ q16, const u16* __restrict__ Z,
                                                  const float* __restrict__ lbuf, u16* __restrict__ y16) {
    __shared__ u16 zb[4][512];
    int wave = threadIdx.x >> 6, lane = threadIdx.x & 63;
    int idx = blockIdx.x * 4 + wave;
    int i = idx >> 4, h = idx & 15;
    uint4 zv = *(const uint4*)(Z + (size_t)h * Z_HSTR + (size_t)i * 512 + lane * 8);
    *(uint4*)&zb[wave][lane * 8] = zv;
    int m = lane >> 3, e = lane & 7;
    const u16* qp = q16 + (size_t)i * CDIM + h * HDIM + m * 8;
    uint4 qb = *(const uint4*)qp;
    float qv[8];
    qv[0] = h2f(qb.x & 0xffff); qv[1] = h2f(qb.x >> 16);
    qv[2] = h2f(qb.y & 0xffff); qv[3] = h2f(qb.y >> 16);
    qv[4] = h2f(qb.z & 0xffff); qv[5] = h2f(qb.z >> 16);
    qv[6] = h2f(qb.w & 0xffff); qv[7] = h2f(qb.w >> 16);
    float linv = 1.f / lbuf[h * T_SEQ + i];
    __syncthreads();
    float acc = 0.f;
#pragma unroll
    for (int a = 0; a < 8; ++a) acc = fmaf(qv[a], h2f(zb[wave][m * 64 + a * 8 + e]), acc);
    y16[(size_t)i * CDIM + h * HDIM + lane] = f2h(acc * linv);
}

extern "C" void kernel_launch(void* const* d_in, const int* in_sizes, int n_in,
                              void* d_out, int out_size, void* d_ws, size_t ws_size,
                              hipStream_t stream) {
    const float* x = (const float*)d_in[0];
    const float* cosb = (const float*)d_in[1];
    const float* sinb = (const float*)d_in[2];
    const float* Wq = (const float*)d_in[3];
    const float* Wk = (const float*)d_in[4];
    const float* Wv = (const float*)d_in[5];
    const float* Wo = (const float*)d_in[6];
    float* out = (float*)d_out;
    char* base = (char*)d_ws;
    // workspace layout (~126 MB total; ws >= 243 MB proven)
    float* qkv = (float*)base;                    // 2048x3072 fp32   25,165,824 B
    float* kc = (float*)(base + 25165824);        // 2048x1024 fp32    8,388,608
    u16* x16 = (u16*)(base + 33554432);           //                   4,194,304
    u16* w16 = (u16*)(base + 37748736);           // 4x 1024x1024 fp16 8,388,608
    u16* q16 = (u16*)(base + 46137344);           //                   4,194,304
    u16* k16 = (u16*)(base + 50331648);           //                   4,194,304
    u16* y16 = (u16*)(base + 54525952);           //                   4,194,304
    u16* W = (u16*)(base + 58720256);             //                  33,554,432
    u16* Z = (u16*)(base + 92274688);             //                  33,554,432
    float* lbuf = (float*)(base + 125829120);     // 16x2048 fp32        131,072

    cvt5<<<dim3(1024, 5), 256, 0, stream>>>(x, Wq, Wk, Wv, Wo, x16, w16);
    hgemm_f32<<<dim3(24, 16), 256, 0, stream>>>(x16, CDIM, w16, CDIM, qkv, 3072, CDIM);
    prep_rope<<<T_SEQ * NHEAD / 4, 256, 0, stream>>>(qkv, q16, k16, kc, cosb, sinb);
    w_pre<<<dim3(32, 16), 256, 0, stream>>>(kc, qkv, W);
    flash_pw<<<1024, 256, 0, stream>>>(q16, k16, W, Z, lbuf);
    contract_y<<<NHEAD * T_SEQ / 4, 256, 0, stream>>>(q16, Z, lbuf, y16);
    hgemm_f32<<<dim3(8, 16), 256, 0, stream>>>(y16, CDIM, w16 + 3145728, CDIM, out, CDIM, CDIM);
}

// Round 9
// 303.997 us; speedup vs baseline: 1.8225x; 1.8225x over previous
//
#include <hip/hip_runtime.h>

typedef unsigned short u16;
typedef unsigned int u32;

#define T_SEQ 2048
#define NHEAD 16
#define HDIM 64
#define CDIM 1024
#define W_HSTR (512*2048)
#define Z_HSTR (2048*512)

// Octonion sign table: SG[a][n] = sign of component (a^n) of e_a * e_n.
// Byte a holds row a; bit n set => negative. (Validated end-to-end rounds 3-8.)
#define SGBITS 0xB2D8741EACC66A00ULL

// exp(s*0.125) = exp2(s*0.125/ln2); extra 2^-12 scale keeps unnormalized Z in fp16 range.
#define EXP2C 0.18033688011112042f

typedef _Float16 f16x8 __attribute__((ext_vector_type(8)));
typedef float f32x4 __attribute__((ext_vector_type(4)));

__device__ __forceinline__ float h2f(u16 u) { _Float16 h; __builtin_memcpy(&h, &u, 2); return (float)h; }
__device__ __forceinline__ u16 f2h(float f) { _Float16 h = (_Float16)f; u16 u; __builtin_memcpy(&u, &h, 2); return u; }
__device__ __forceinline__ u32 pk(float a, float b) { return (u32)f2h(a) | ((u32)f2h(b) << 16); }

// async 16B/lane global->LDS DMA; lds dest wave-uniform (HW adds lane*16)
__device__ __forceinline__ void gload16(const u16* g, u16* l) {
    __builtin_amdgcn_global_load_lds((const __attribute__((address_space(1))) u32*)g,
                                     (__attribute__((address_space(3))) u32*)l, 16, 0, 0);
}

// ---- MFMA tile core (conflict-free fragment-major LDS; rounds 6-8) ----
template<bool F16OUT>
__device__ __forceinline__ void hgemm_tile(const u16* __restrict__ At, int lda,
                                           const u16* __restrict__ Bt, int ldb, int K,
                                           float* __restrict__ Cf, u16* __restrict__ Ch,
                                           int ldc, float scale, u16* As, u16* Bs) {
    int t = threadIdx.x;
    int wave = t >> 6, l = t & 63;
    int wm = wave & 1, wn = wave >> 1;
    int quad = l >> 4, lr = l & 15;
    f32x4 acc[4][4];
#pragma unroll
    for (int i = 0; i < 4; ++i)
#pragma unroll
        for (int j = 0; j < 4; ++j) acc[i][j] = (f32x4){0.f, 0.f, 0.f, 0.f};
    int acol = quad * 8;
    for (int k0 = 0; k0 < K; k0 += 64) {
#pragma unroll
        for (int j = 0; j < 4; ++j) {
            int d = wave * 4 + j;
            int kb = d >> 3, seg = d & 7;
            size_t roff = (size_t)(seg * 16 + lr);
            int coff = k0 + kb * 32 + acol;
            gload16(At + roff * lda + coff, As + d * 512);
            gload16(Bt + roff * ldb + coff, Bs + d * 512);
        }
        __syncthreads();
#pragma unroll
        for (int kb = 0; kb < 2; ++kb) {
            f16x8 af[4], bf[4];
#pragma unroll
            for (int mi = 0; mi < 4; ++mi) af[mi] = *(const f16x8*)&As[(kb * 8 + wm * 4 + mi) * 512 + l * 8];
#pragma unroll
            for (int ni = 0; ni < 4; ++ni) bf[ni] = *(const f16x8*)&Bs[(kb * 8 + wn * 4 + ni) * 512 + l * 8];
#pragma unroll
            for (int mi = 0; mi < 4; ++mi)
#pragma unroll
                for (int ni = 0; ni < 4; ++ni)
                    acc[mi][ni] = __builtin_amdgcn_mfma_f32_16x16x32_f16(af[mi], bf[ni], acc[mi][ni], 0, 0, 0);
        }
        __syncthreads();
    }
#pragma unroll
    for (int mi = 0; mi < 4; ++mi)
#pragma unroll
        for (int ni = 0; ni < 4; ++ni)
#pragma unroll
            for (int rr = 0; rr < 4; ++rr) {
                int gr = wm * 64 + mi * 16 + quad * 4 + rr;
                int gc = wn * 64 + ni * 16 + lr;
                float v = acc[mi][ni][rr] * scale;
                if (F16OUT) Ch[(size_t)gr * ldc + gc] = f2h(v);
                else Cf[(size_t)gr * ldc + gc] = v;
            }
}

__global__ __launch_bounds__(256) void hgemm_f32(const u16* __restrict__ A, int lda,
                                                 const u16* __restrict__ B, int ldb,
                                                 float* __restrict__ C, int ldc, int K) {
    __shared__ u16 As[8192], Bs[8192];
    int bm = blockIdx.y * 128, bn = blockIdx.x * 128;
    hgemm_tile<false>(A + (size_t)bm * lda, lda, B + (size_t)bn * ldb, ldb, K,
                      C + (size_t)bm * ldc + bn, nullptr, ldc, 1.f, As, Bs);
}

__global__ __launch_bounds__(256) void hgemm_f16(const u16* __restrict__ A, int lda,
                                                 const u16* __restrict__ B, int ldb,
                                                 u16* __restrict__ C, int ldc, int K) {
    __shared__ u16 As[8192], Bs[8192];
    int bm = blockIdx.y * 128, bn = blockIdx.x * 128;
    hgemm_tile<true>(A + (size_t)bm * lda, lda, B + (size_t)bn * ldb, ldb, K,
                     nullptr, C + (size_t)bm * ldc + bn, ldc, 1.f, As, Bs);
}

// ---- fused causal attention core, software-pipelined (dbuf P, 1 barrier/cb) ----
// per cb: QK-MFMA(cb) ; PW-MFMA(cb-1) from Pl[cur] ; exp(cb) -> Pl[cur^1].
// l = P.1 only on nq==0 blocks; 1/l deferred to contract_y (round-8-validated).
__global__ __launch_bounds__(256, 2) void flash_pw(const u16* __restrict__ q16,
                                                   const u16* __restrict__ k16,
                                                   const u16* __restrict__ W,
                                                   u16* __restrict__ Z,
                                                   float* __restrict__ lbuf) {
    __shared__ u16 Pl[2][128 * 136];
    int idx = blockIdx.x;
    int rb = 15 - (idx >> 6);
    int i6 = idx & 63;
    int h = ((i6 & 7) << 1) | ((i6 >> 3) & 1);  // same-h blocks share an XCD (L2 W-locality)
    int nq = i6 >> 4;
    int t = threadIdx.x;
    int wave = t >> 6, l = t & 63;
    int wm = wave & 1, wn = wave >> 1;
    int quad = l >> 4, lr = l & 15;

    const u16* qbase = q16 + (size_t)(rb * 128 + wm * 64 + lr) * CDIM + h * HDIM + quad * 8;
    f16x8 qa[4][2];
#pragma unroll
    for (int mi = 0; mi < 4; ++mi)
#pragma unroll
        for (int kb = 0; kb < 2; ++kb)
            qa[mi][kb] = *(const f16x8*)(qbase + (size_t)(mi * 16) * CDIM + kb * 32);

    f32x4 accz[4][4];
    f32x4 accl[4];
#pragma unroll
    for (int mi = 0; mi < 4; ++mi) {
        accl[mi] = (f32x4){0.f, 0.f, 0.f, 0.f};
#pragma unroll
        for (int ni = 0; ni < 4; ++ni) accz[mi][ni] = (f32x4){0.f, 0.f, 0.f, 0.f};
    }
    f16x8 ones;
#pragma unroll
    for (int j = 0; j < 8; ++j) ones[j] = (_Float16)1.0f;

    const u16* kbase = k16 + (size_t)(wn * 64 + lr) * CDIM + h * HDIM + quad * 8;
    const u16* Wbase = W + (size_t)h * W_HSTR + (size_t)(nq * 128 + wn * 64 + lr) * T_SEQ + quad * 8;

    auto qk = [&](int cb, f32x4 (&s)[4][4]) {
        f16x8 kf[4][2];
#pragma unroll
        for (int ni = 0; ni < 4; ++ni)
#pragma unroll
            for (int kb = 0; kb < 2; ++kb)
                kf[ni][kb] = *(const f16x8*)(kbase + (size_t)(cb * 128 + ni * 16) * CDIM + kb * 32);
#pragma unroll
        for (int mi = 0; mi < 4; ++mi)
#pragma unroll
            for (int ni = 0; ni < 4; ++ni) s[mi][ni] = (f32x4){0.f, 0.f, 0.f, 0.f};
#pragma unroll
        for (int kb = 0; kb < 2; ++kb)
#pragma unroll
            for (int mi = 0; mi < 4; ++mi)
#pragma unroll
                for (int ni = 0; ni < 4; ++ni)
                    s[mi][ni] = __builtin_amdgcn_mfma_f32_16x16x32_f16(qa[mi][kb], kf[ni][kb], s[mi][ni], 0, 0, 0);
    };
    auto expst = [&](int cb, f32x4 (&s)[4][4], u16* Pd) {
#pragma unroll
        for (int mi = 0; mi < 4; ++mi) {
            int row = wm * 64 + mi * 16 + quad * 4;
#pragma unroll
            for (int ni = 0; ni < 4; ++ni) {
                int col = wn * 64 + ni * 16 + lr;
#pragma unroll
                for (int rr = 0; rr < 4; ++rr) {
                    bool valid = (cb < rb) | (col <= row + rr);
                    float p = valid ? __builtin_amdgcn_exp2f(s[mi][ni][rr] * EXP2C - 12.f) : 0.f;
                    Pd[(row + rr) * 136 + col] = f2h(p);
                }
            }
        }
    };
    auto pw = [&](int cb, const u16* Ps) {
#pragma unroll
        for (int kb = 0; kb < 4; ++kb) {
            f16x8 pf[4], wf[4];
#pragma unroll
            for (int ni = 0; ni < 4; ++ni)
                wf[ni] = *(const f16x8*)(Wbase + (size_t)(ni * 16) * T_SEQ + cb * 128 + kb * 32);
#pragma unroll
            for (int mi = 0; mi < 4; ++mi)
                pf[mi] = *(const f16x8*)&Ps[(wm * 64 + mi * 16 + lr) * 136 + kb * 32 + quad * 8];
#pragma unroll
            for (int mi = 0; mi < 4; ++mi) {
#pragma unroll
                for (int ni = 0; ni < 4; ++ni)
                    accz[mi][ni] = __builtin_amdgcn_mfma_f32_16x16x32_f16(pf[mi], wf[ni], accz[mi][ni], 0, 0, 0);
                if (nq == 0)
                    accl[mi] = __builtin_amdgcn_mfma_f32_16x16x32_f16(pf[mi], ones, accl[mi], 0, 0, 0);
            }
        }
    };

    {   // prologue: tile 0
        f32x4 s[4][4];
        qk(0, s);
        expst(0, s, Pl[0]);
    }
    int cur = 0;
    for (int cb = 1; cb <= rb; ++cb) {
        __syncthreads();
        f32x4 s[4][4];
        qk(cb, s);              // MFMA stream (indep of Pl[cur])
        pw(cb - 1, Pl[cur]);    // MFMA stream from LDS
        expst(cb, s, Pl[cur ^ 1]);  // VALU stream -> other buffer
        cur ^= 1;
    }
    __syncthreads();
    pw(rb, Pl[cur]);

    u16* Zb = Z + (size_t)h * Z_HSTR;
#pragma unroll
    for (int mi = 0; mi < 4; ++mi)
#pragma unroll
        for (int rr = 0; rr < 4; ++rr) {
            int row = rb * 128 + wm * 64 + mi * 16 + quad * 4 + rr;
#pragma unroll
            for (int ni = 0; ni < 4; ++ni) {
                int col = nq * 128 + wn * 64 + ni * 16 + lr;
                Zb[(size_t)row * 512 + col] = f2h(accz[mi][ni][rr]);
            }
        }
    if (nq == 0 && lr == 0) {
#pragma unroll
        for (int mi = 0; mi < 4; ++mi) {
            int row = rb * 128 + wm * 64 + mi * 16 + quad * 4;
            *(f32x4*)(lbuf + h * T_SEQ + row) = accl[mi];
        }
    }
}

// fp32 -> fp16 conversions: z=0 x(2M), z=1..4 Wq/Wk/Wv/Wo (1M each) into w16
__global__ __launch_bounds__(256) void cvt5(const float* __restrict__ x, const float* __restrict__ wq,
                                            const float* __restrict__ wk, const float* __restrict__ wv,
                                            const float* __restrict__ wo,
                                            u16* __restrict__ x16, u16* __restrict__ w16) {
    int z = blockIdx.y;
    size_t base = ((size_t)blockIdx.x * 256 + threadIdx.x) * 8;
    const float* src;
    u16* dst;
    size_t cnt;
    if (z == 0) { src = x; dst = x16; cnt = 2097152; }
    else if (z == 1) { src = wq; dst = w16; cnt = 1048576; }
    else if (z == 2) { src = wk; dst = w16 + 1048576; cnt = 1048576; }
    else if (z == 3) { src = wv; dst = w16 + 2097152; cnt = 1048576; }
    else { src = wo; dst = w16 + 3145728; cnt = 1048576; }
    if (base >= cnt) return;
    float4 f0 = *(const float4*)(src + base);
    float4 f1 = *(const float4*)(src + base + 4);
    uint4 o;
    o.x = pk(f0.x, f0.y); o.y = pk(f0.z, f0.w); o.z = pk(f1.x, f1.y); o.w = pk(f1.z, f1.w);
    *(uint4*)(dst + base) = o;
}

// One wave per (t,h): rotary+RMS from fp16 qkv (ld 3072); writes q16,k16 (fp16), kc (fp32).
__global__ __launch_bounds__(256) void prep_rope(const u16* __restrict__ qkv,
                                                 u16* __restrict__ q16, u16* __restrict__ k16,
                                                 float* __restrict__ kc,
                                                 const float* __restrict__ cosb, const float* __restrict__ sinb) {
    int wave = threadIdx.x >> 6, lane = threadIdx.x & 63;
    int idx = blockIdx.x * 4 + wave;
    int t = idx >> 4, h = idx & 15;
    int d = lane & 31;
    float cs = cosb[t * 32 + d];
    float sn = sinb[t * 32 + d];
    size_t b3 = (size_t)t * 3072 + h * HDIM;
    size_t b1 = (size_t)t * CDIM + h * HDIM;

    float xq = h2f(qkv[b3 + lane]);
    float oq = __shfl(xq, lane ^ 32);
    float rq = (lane < 32) ? fmaf(xq, cs, oq * sn) : fmaf(xq, cs, -oq * sn);
    float ssq = rq * rq;
#pragma unroll
    for (int m = 1; m < 64; m <<= 1) ssq += __shfl_xor(ssq, m);
    rq *= rsqrtf(ssq * (1.f / 64.f) + 1e-6f);
    q16[b1 + lane] = f2h(rq);

    float xk = h2f(qkv[b3 + 1024 + lane]);
    float ok = __shfl(xk, lane ^ 32);
    float rk = (lane < 32) ? fmaf(xk, cs, ok * sn) : fmaf(xk, cs, -ok * sn);
    float ssk = rk * rk;
#pragma unroll
    for (int m = 1; m < 64; m <<= 1) ssk += __shfl_xor(ssk, m);
    rk *= rsqrtf(ssk * (1.f / 64.f) + 1e-6f);
    k16[b1 + lane] = f2h(rk);

    float s8 = rk * rk;
    s8 += __shfl_xor(s8, 1); s8 += __shfl_xor(s8, 2); s8 += __shfl_xor(s8, 4);
    float sc2 = 1.f / fmaxf(sqrtf(s8), 1e-12f);
    float kcv = rk * sc2;
    if (lane & 7) kcv = -kcv;  // octonion conjugate
    kc[b1 + lane] = kcv;
}

// W[h][n=(m*64+a*8+e)][j] from kc (fp32, ld 1024) and v inside fp16 qkv (ld 3072, +2048)
__global__ __launch_bounds__(256) void w_pre(const float* __restrict__ kc, const u16* __restrict__ qkv,
                                             u16* __restrict__ W) {
    __shared__ float kcs[64][65];
    __shared__ float vs[64][65];
    int h = blockIdx.y;
    int j0 = blockIdx.x * 64;
    int t = threadIdx.x;
    int r = t >> 2, cq = (t & 3) * 16;
    const float* kp = kc + (size_t)(j0 + r) * CDIM + h * HDIM + cq;
    const u16* vp = qkv + (size_t)(j0 + r) * 3072 + 2048 + h * HDIM + cq;
#pragma unroll
    for (int u4 = 0; u4 < 4; ++u4) {
        float4 a = *(const float4*)(kp + u4 * 4);
        ushort4 b = *(const ushort4*)(vp + u4 * 4);
        kcs[r][cq + u4 * 4 + 0] = a.x; kcs[r][cq + u4 * 4 + 1] = a.y;
        kcs[r][cq + u4 * 4 + 2] = a.z; kcs[r][cq + u4 * 4 + 3] = a.w;
        vs[r][cq + u4 * 4 + 0] = h2f(b.x); vs[r][cq + u4 * 4 + 1] = h2f(b.y);
        vs[r][cq + u4 * 4 + 2] = h2f(b.z); vs[r][cq + u4 * 4 + 3] = h2f(b.w);
    }
    __syncthreads();
    int j = t & 63, g = t >> 6;
    u16* Wp = W + (size_t)h * W_HSTR + j0 + j;
    for (int ae = g * 16; ae < g * 16 + 16; ++ae) {
        int a = ae >> 3, e = ae & 7;
        u32 mask = 0;
#pragma unroll
        for (int qq = 0; qq < 8; ++qq) {
            int p = a ^ e ^ qq;
            u32 bit = (u32)(((SGBITS >> (a * 8 + p)) ^ (SGBITS >> ((e ^ qq) * 8 + qq))) & 1ULL);
            mask |= bit << qq;
        }
#pragma unroll
        for (int m = 0; m < 8; ++m) {
            float w = 0.f;
#pragma unroll
            for (int qq = 0; qq < 8; ++qq) {
                float t1 = kcs[j][m * 8 + (a ^ e ^ qq)] * vs[j][m * 8 + qq];
                w = ((mask >> qq) & 1) ? (w - t1) : (w + t1);
            }
            Wp[(size_t)(m * 64 + ae) * T_SEQ] = f2h(w);
        }
    }
}

// y16[i, h*64+m*8+e] = (sum_a q16[..m*8+a] * Z'[h][i][m*64+a*8+e]) / l[h][i]
__global__ __launch_bounds__(256) void contract_y(const u16* __restrict__ q16, const u16* __restrict__ Z,
                                                  const float* __restrict__ lbuf, u16* __restrict__ y16) {
    __shared__ u16 zb[4][512];
    int wave = threadIdx.x >> 6, lane = threadIdx.x & 63;
    int idx = blockIdx.x * 4 + wave;
    int i = idx >> 4, h = idx & 15;
    uint4 zv = *(const uint4*)(Z + (size_t)h * Z_HSTR + (size_t)i * 512 + lane * 8);
    *(uint4*)&zb[wave][lane * 8] = zv;
    int m = lane >> 3, e = lane & 7;
    const u16* qp = q16 + (size_t)i * CDIM + h * HDIM + m * 8;
    uint4 qb = *(const uint4*)qp;
    float qv[8];
    qv[0] = h2f(qb.x & 0xffff); qv[1] = h2f(qb.x >> 16);
    qv[2] = h2f(qb.y & 0xffff); qv[3] = h2f(qb.y >> 16);
    qv[4] = h2f(qb.z & 0xffff); qv[5] = h2f(qb.z >> 16);
    qv[6] = h2f(qb.w & 0xffff); qv[7] = h2f(qb.w >> 16);
    float linv = 1.f / lbuf[h * T_SEQ + i];
    __syncthreads();
    float acc = 0.f;
#pragma unroll
    for (int a = 0; a < 8; ++a) acc = fmaf(qv[a], h2f(zb[wave][m * 64 + a * 8 + e]), acc);
    y16[(size_t)i * CDIM + h * HDIM + lane] = f2h(acc * linv);
}

extern "C" void kernel_launch(void* const* d_in, const int* in_sizes, int n_in,
                              void* d_out, int out_size, void* d_ws, size_t ws_size,
                              hipStream_t stream) {
    const float* x = (const float*)d_in[0];
    const float* cosb = (const float*)d_in[1];
    const float* sinb = (const float*)d_in[2];
    const float* Wq = (const float*)d_in[3];
    const float* Wk = (const float*)d_in[4];
    const float* Wv = (const float*)d_in[5];
    const float* Wo = (const float*)d_in[6];
    float* out = (float*)d_out;
    char* base = (char*)d_ws;
    // workspace layout (~113 MB total; ws >= 243 MB proven)
    u16* qkv16 = (u16*)base;                      // 2048x3072 fp16   12,582,912 B
    float* kc = (float*)(base + 12582912);        // 2048x1024 fp32    8,388,608
    u16* x16 = (u16*)(base + 20971520);           //                   4,194,304
    u16* w16 = (u16*)(base + 25165824);           // 4x 1024x1024 fp16 8,388,608
    u16* q16 = (u16*)(base + 33554432);           //                   4,194,304
    u16* k16 = (u16*)(base + 37748736);           //                   4,194,304
    u16* y16 = (u16*)(base + 41943040);           //                   4,194,304
    u16* W = (u16*)(base + 46137344);             //                  33,554,432
    u16* Z = (u16*)(base + 79691776);             //                  33,554,432
    float* lbuf = (float*)(base + 113246208);     // 16x2048 fp32        131,072

    cvt5<<<dim3(1024, 5), 256, 0, stream>>>(x, Wq, Wk, Wv, Wo, x16, w16);
    hgemm_f16<<<dim3(24, 16), 256, 0, stream>>>(x16, CDIM, w16, CDIM, qkv16, 3072, CDIM);
    prep_rope<<<T_SEQ * NHEAD / 4, 256, 0, stream>>>(qkv16, q16, k16, kc, cosb, sinb);
    w_pre<<<dim3(32, 16), 256, 0, stream>>>(kc, qkv16, W);
    flash_pw<<<1024, 256, 0, stream>>>(q16, k16, W, Z, lbuf);
    contract_y<<<NHEAD * T_SEQ / 4, 256, 0, stream>>>(q16, Z, lbuf, y16);
    hgemm_f32<<<dim3(8, 16), 256, 0, stream>>>(y16, CDIM, w16 + 3145728, CDIM, out, CDIM, CDIM);
}